// Round 3
// baseline (337.409 us; speedup 1.0000x reference)
//
#include <hip/hip_runtime.h>
#include <hip/hip_bf16.h>
#include <math.h>

#define EPS 1e-6f

// ---------------------------------------------------------------------------
// K1: y[m,p] = sum_c x[b,c,hw] * w1[p,c]     (m = b*4096 + hw)
// ---------------------------------------------------------------------------
__global__ __launch_bounds__(256) void k_conv1x1(const float* __restrict__ x,
                                                 const float* __restrict__ w1,
                                                 float* __restrict__ y) {
  __shared__ float As[64][68];  // [k(c)][m]
  __shared__ float Bs[64][68];  // [k(c)][p]
  const int t = threadIdx.x;
  const int m0 = blockIdx.x * 64, p0 = blockIdx.y * 64;
  const int b = m0 >> 12, hw0 = m0 & 4095;
  const int ml = t & 63, c0 = t >> 6;
  const int rl = t >> 2, kq = t & 3;
  const int tn = t & 15, tm = t >> 4;
  float acc[4][4] = {};
  for (int kk = 0; kk < 128; kk += 64) {
    __syncthreads();
#pragma unroll
    for (int i = 0; i < 16; ++i)
      As[c0 + i * 4][ml] = x[(size_t)(b * 128 + kk + c0 + i * 4) * 4096 + hw0 + ml];
#pragma unroll
    for (int j = 0; j < 4; ++j) {
      const int f = kq + j * 4;
      const float4 v = *(const float4*)(w1 + (size_t)(p0 + rl) * 128 + kk + f * 4);
      Bs[f * 4 + 0][rl] = v.x;
      Bs[f * 4 + 1][rl] = v.y;
      Bs[f * 4 + 2][rl] = v.z;
      Bs[f * 4 + 3][rl] = v.w;
    }
    __syncthreads();
#pragma unroll 8
    for (int k = 0; k < 64; ++k) {
      const float4 a = *(const float4*)(&As[k][tm * 4]);
      const float4 bb = *(const float4*)(&Bs[k][tn * 4]);
      const float av[4] = {a.x, a.y, a.z, a.w};
      const float bv[4] = {bb.x, bb.y, bb.z, bb.w};
#pragma unroll
      for (int i = 0; i < 4; ++i)
#pragma unroll
        for (int j = 0; j < 4; ++j) acc[i][j] += av[i] * bv[j];
    }
  }
#pragma unroll
  for (int i = 0; i < 4; ++i) {
    const float4 v = {acc[i][0], acc[i][1], acc[i][2], acc[i][3]};
    *(float4*)(y + (size_t)(m0 + tm * 4 + i) * 256 + p0 + tn * 4) = v;
  }
}

// ---------------------------------------------------------------------------
// K2: depthwise 3x3 SAME + bias, NHWC layout in/out.
// ---------------------------------------------------------------------------
__global__ __launch_bounds__(256) void k_dwconv(const float* __restrict__ y,
                                                const float* __restrict__ w3,
                                                const float* __restrict__ b3,
                                                float* __restrict__ xm) {
  __shared__ float wt[9][256];
  __shared__ float bs[256];
  const int t = threadIdx.x;
#pragma unroll
  for (int i = 0; i < 9; ++i) wt[i][t] = w3[t * 9 + i];
  bs[t] = b3[t];
  __syncthreads();
  const int sub = t >> 6;
  const int pq = t & 63;
  const int m = blockIdx.x * 4 + sub;
  const int hw = m & 4095;
  const int h = hw >> 6, w = hw & 63;
  const int bb = m >> 12;
  float4 acc = *(const float4*)(&bs[pq * 4]);
#pragma unroll
  for (int dy = -1; dy <= 1; ++dy) {
    const int hh = h + dy;
    if (hh < 0 || hh > 63) continue;
#pragma unroll
    for (int dx = -1; dx <= 1; ++dx) {
      const int ww = w + dx;
      if (ww < 0 || ww > 63) continue;
      const int idx = (dy + 1) * 3 + (dx + 1);
      const float4 v =
          *(const float4*)(y + (size_t)((bb << 12) + (hh << 6) + ww) * 256 + pq * 4);
      const float4 wv = *(const float4*)(&wt[idx][pq * 4]);
      acc.x += v.x * wv.x;
      acc.y += v.y * wv.y;
      acc.z += v.z * wv.z;
      acc.w += v.w * wv.w;
    }
  }
  *(float4*)(xm + (size_t)m * 256 + pq * 4) = acc;
}

// ---------------------------------------------------------------------------
// K3: xl = relu(xm @ lower_w^T + lb).
// ---------------------------------------------------------------------------
__global__ __launch_bounds__(256) void k_lower(const float* __restrict__ xm,
                                               const float* __restrict__ lw,
                                               const float* __restrict__ lb,
                                               float* __restrict__ xl) {
  __shared__ float As[64][68];
  __shared__ float Bs[64][68];
  const int t = threadIdx.x;
  const int m0 = blockIdx.x * 64, n0 = blockIdx.y * 64;
  const int rl = t >> 2, kq = t & 3;
  const int tn = t & 15, tm = t >> 4;
  float acc[4][4] = {};
  for (int kk = 0; kk < 256; kk += 64) {
    __syncthreads();
#pragma unroll
    for (int j = 0; j < 4; ++j) {
      const int f = kq + j * 4;
      const float4 a = *(const float4*)(xm + (size_t)(m0 + rl) * 256 + kk + f * 4);
      As[f * 4 + 0][rl] = a.x;
      As[f * 4 + 1][rl] = a.y;
      As[f * 4 + 2][rl] = a.z;
      As[f * 4 + 3][rl] = a.w;
      const float4 bq = *(const float4*)(lw + (size_t)(n0 + rl) * 256 + kk + f * 4);
      Bs[f * 4 + 0][rl] = bq.x;
      Bs[f * 4 + 1][rl] = bq.y;
      Bs[f * 4 + 2][rl] = bq.z;
      Bs[f * 4 + 3][rl] = bq.w;
    }
    __syncthreads();
#pragma unroll 8
    for (int k = 0; k < 64; ++k) {
      const float4 a = *(const float4*)(&As[k][tm * 4]);
      const float4 bb = *(const float4*)(&Bs[k][tn * 4]);
      const float av[4] = {a.x, a.y, a.z, a.w};
      const float bv[4] = {bb.x, bb.y, bb.z, bb.w};
#pragma unroll
      for (int i = 0; i < 4; ++i)
#pragma unroll
        for (int j = 0; j < 4; ++j) acc[i][j] += av[i] * bv[j];
    }
  }
  const float4 bias4 = *(const float4*)(lb + n0 + tn * 4);
  const float bias[4] = {bias4.x, bias4.y, bias4.z, bias4.w};
#pragma unroll
  for (int i = 0; i < 4; ++i) {
    float4 v;
    v.x = fmaxf(acc[i][0] + bias[0], 0.f);
    v.y = fmaxf(acc[i][1] + bias[1], 0.f);
    v.z = fmaxf(acc[i][2] + bias[2], 0.f);
    v.w = fmaxf(acc[i][3] + bias[3], 0.f);
    *(float4*)(xl + (size_t)(m0 + tm * 4 + i) * 256 + n0 + tn * 4) = v;
  }
}

// ---------------------------------------------------------------------------
// K4a: fast EM path. bases_init = v/max(|v|,1e-12) == 1.0f exactly whenever
// v >= 1e-12, so (almost always) all 16 bases start identical => every r
// column stays identical through all iterations. Whole EM collapses to
// scalar recurrences per pixel row:
//   C' = C*s*B / (16*C*B^2 + eps);  B' = B*num/(den+eps),
//   num = sum_n s*C', den = 16*B*sum_n C'^2;  xr = 16*B*C''.
// One wave per pixel, lane owns 4 rows; waves with any binit != 1 skip
// (handled by k_em_slow).
// ---------------------------------------------------------------------------
__global__ __launch_bounds__(256) void k_em_fast(const float* xl,
                                                 const float* __restrict__ binit,
                                                 const float* __restrict__ xmp,
                                                 float* feat) {
  const int lane = threadIdx.x & 63;
  const int m = blockIdx.x * 4 + (threadIdx.x >> 6);
  const float bv0 = binit[m * 16 + (lane & 15)];
  if (!__all(bv0 == 1.0f)) return;  // asymmetric pixel -> slow kernel
  const float4 s4 = *(const float4*)(xl + (size_t)m * 256 + lane * 4);
  const float s[4] = {s4.x, s4.y, s4.z, s4.w};
  float C[4] = {0.0625f, 0.0625f, 0.0625f, 0.0625f};
  float Bv = 1.f;
  for (int step = 0; step < 6; ++step) {
    const float k1 = 16.f * Bv * Bv;
    float pnum = 0.f, psq = 0.f;
#pragma unroll
    for (int i = 0; i < 4; ++i) {
      const float den = fmaf(C[i], k1, EPS);
      const float cn = C[i] * (s[i] * Bv) * __builtin_amdgcn_rcpf(den);
      C[i] = cn;
      pnum = fmaf(s[i], cn, pnum);
      psq = fmaf(cn, cn, psq);
    }
#pragma unroll
    for (int d = 1; d < 64; d <<= 1) {
      pnum += __shfl_xor(pnum, d, 64);
      psq += __shfl_xor(psq, d, 64);
    }
    const float den2 = fmaf(16.f * Bv, psq, EPS);
    Bv = Bv * pnum * __builtin_amdgcn_rcpf(den2);
  }
  const float4 xm4 = *(const float4*)(xmp + (size_t)m * 256 + lane * 4);
  const float xmv[4] = {xm4.x, xm4.y, xm4.z, xm4.w};
  const float k1 = 16.f * Bv * Bv;
  float o[4];
#pragma unroll
  for (int i = 0; i < 4; ++i) {
    const float den = fmaf(C[i], k1, EPS);
    const float cn = C[i] * (s[i] * Bv) * __builtin_amdgcn_rcpf(den);
    const float xr = 16.f * Bv * cn;
    o[i] = fmaxf(xmv[i] + xr, 0.f);
  }
  const float4 outv = {o[0], o[1], o[2], o[3]};
  *(float4*)(feat + (size_t)m * 256 + lane * 4) = outv;
}

// ---------------------------------------------------------------------------
// K4b: general EM fallback for pixels whose bases_init are not all 1.0
// (exact-zero uniform draws etc.). Early-exits for symmetric pixels.
// Identical math to the validated round-2 kernel.
// ---------------------------------------------------------------------------
__global__ __launch_bounds__(256, 2) void k_em_slow(const float* xl,
                                                    const float* __restrict__ binit,
                                                    const float* __restrict__ xmp,
                                                    float* feat) {
  const int lane = threadIdx.x & 63;
  const int m = blockIdx.x * 4 + (threadIdx.x >> 6);
  const float bv0 = binit[m * 16 + (lane & 15)];
  if (__all(bv0 == 1.0f)) return;  // handled by fast kernel
  const float4 s4 = *(const float4*)(xl + (size_t)m * 256 + lane * 4);
  const float s[4] = {s4.x, s4.y, s4.z, s4.w};
  float b[16];
#pragma unroll
  for (int r = 0; r < 16; ++r) {
    const float v = binit[m * 16 + r];
    b[r] = v / fmaxf(fabsf(v), 1e-12f);
  }
  float c[4][16];
#pragma unroll
  for (int i = 0; i < 4; ++i) {
    float mx = s[i] * b[0];
#pragma unroll
    for (int r = 1; r < 16; ++r) mx = fmaxf(mx, s[i] * b[r]);
    float sum = 0.f;
#pragma unroll
    for (int r = 0; r < 16; ++r) {
      const float e = __expf(s[i] * b[r] - mx);
      c[i][r] = e;
      sum += e;
    }
    const float inv = __fdividef(1.f, sum);
#pragma unroll
    for (int r = 0; r < 16; ++r) c[i][r] *= inv;
  }
  for (int step = 0; step < 6; ++step) {
    float red[32];
#pragma unroll
    for (int r = 0; r < 32; ++r) red[r] = 0.f;
#pragma unroll
    for (int i = 0; i < 4; ++i) {
      float tt = 0.f;
#pragma unroll
      for (int r = 0; r < 16; ++r) tt += c[i][r] * b[r];
      float tp = 0.f;
#pragma unroll
      for (int r = 0; r < 16; ++r) {
        const float cn = c[i][r] * (s[i] * b[r]) * __frcp_rn(tt * b[r] + EPS);
        c[i][r] = cn;
        tp += cn * b[r];
        red[r] += s[i] * cn;
      }
#pragma unroll
      for (int r = 0; r < 16; ++r) red[16 + r] += tp * c[i][r];
    }
    int cnt = 32;
#pragma unroll
    for (int k = 4; k >= 0; --k) {
      const int d = 1 << k;
      const bool up = (lane >> k) & 1;
      const int half = cnt >> 1;
#pragma unroll
      for (int j = 0; j < half; ++j) {
        const float lo = red[j], hi = red[j + half];
        const float send = up ? lo : hi;
        const float recv = __shfl_xor(send, d, 64);
        red[j] = (up ? hi : lo) + recv;
      }
      cnt = half;
    }
    float S = red[0] + __shfl_xor(red[0], 32, 64);
    const float dpart = __shfl_xor(S, 16, 64);
    const float q = S * __frcp_rn(dpart + EPS);
#pragma unroll
    for (int r = 0; r < 16; ++r) b[r] *= __shfl(q, r, 64);
  }
  const float4 xm4 = *(const float4*)(xmp + (size_t)m * 256 + lane * 4);
  const float xmv[4] = {xm4.x, xm4.y, xm4.z, xm4.w};
  float o4[4];
#pragma unroll
  for (int i = 0; i < 4; ++i) {
    float tt = 0.f;
#pragma unroll
    for (int r = 0; r < 16; ++r) tt += c[i][r] * b[r];
    float xr = 0.f;
#pragma unroll
    for (int r = 0; r < 16; ++r) {
      const float cn = c[i][r] * (s[i] * b[r]) * __frcp_rn(tt * b[r] + EPS);
      xr += b[r] * cn;
    }
    o4[i] = fmaxf(xmv[i] + xr, 0.f);
  }
  const float4 outv = {o4[0], o4[1], o4[2], o4[3]};
  *(float4*)(feat + (size_t)m * 256 + lane * 4) = outv;
}

// ---------------------------------------------------------------------------
// K5: pooling phase 1
// ---------------------------------------------------------------------------
__global__ __launch_bounds__(256) void k_pool1(const float* __restrict__ feat,
                                               float* __restrict__ psum,
                                               float* __restrict__ pmax) {
  const int t = threadIdx.x;
  const int b = blockIdx.x >> 6;
  const int ch = blockIdx.x & 63;
  const float* fp = feat + (size_t)(b * 4096 + ch * 64) * 256 + t;
  float sum = 0.f, mx = -1e30f;
#pragma unroll 8
  for (int r = 0; r < 64; ++r) {
    const float v = fp[(size_t)r * 256];
    sum += v;
    mx = fmaxf(mx, v);
  }
  psum[(size_t)blockIdx.x * 256 + t] = sum;
  pmax[(size_t)blockIdx.x * 256 + t] = mx;
}

// ---------------------------------------------------------------------------
// K6: finish pooling + channel-attention MLP + sigmoid
// ---------------------------------------------------------------------------
__global__ __launch_bounds__(256) void k_att(const float* __restrict__ psum,
                                             const float* __restrict__ pmax,
                                             const float* __restrict__ ca1,
                                             const float* __restrict__ ca2,
                                             float* __restrict__ attv,
                                             float* __restrict__ out_att) {
  __shared__ float sA[256], sM[256], sH[64];
  const int t = threadIdx.x;
  const int b = blockIdx.x;
  float sum = 0.f, mx = -1e30f;
#pragma unroll 8
  for (int ch = 0; ch < 64; ++ch) {
    sum += psum[(size_t)(b * 64 + ch) * 256 + t];
    mx = fmaxf(mx, pmax[(size_t)(b * 64 + ch) * 256 + t]);
  }
  sA[t] = sum * (1.0f / 4096.0f);
  sM[t] = mx;
  __syncthreads();
  if (t < 64) {
    float ha = 0.f, hm = 0.f;
#pragma unroll 8
    for (int p = 0; p < 256; ++p) {
      const float w = ca1[t * 256 + p];
      ha += sA[p] * w;
      hm += sM[p] * w;
    }
    sH[t] = fmaxf(ha, 0.f) + fmaxf(hm, 0.f);
  }
  __syncthreads();
  float logit = 0.f;
#pragma unroll 8
  for (int a = 0; a < 64; ++a) logit += sH[a] * ca2[t * 64 + a];
  const float av = 1.0f / (1.0f + expf(-logit));
  attv[b * 256 + t] = av;
  out_att[b * 256 + t] = av;
}

// ---------------------------------------------------------------------------
// K7: out[b,o,hw] = sum_p feat[m,p]*att[b,p]*fc_w[o,p] + fc_b[o]
// ---------------------------------------------------------------------------
__global__ __launch_bounds__(256) void k_fc(const float* __restrict__ feat,
                                            const float* __restrict__ attv,
                                            const float* __restrict__ fw,
                                            const float* __restrict__ fb,
                                            float* __restrict__ out) {
  __shared__ float As[64][68];
  __shared__ float Bs[64][68];
  const int t = threadIdx.x;
  const int m0 = blockIdx.x * 64, o0 = blockIdx.y * 64;
  const int b = m0 >> 12, hw0 = m0 & 4095;
  const int rl = t >> 2, kq = t & 3;
  const int tm = t & 15, tn = t >> 4;
  float acc[4][4] = {};
  for (int kk = 0; kk < 256; kk += 64) {
    __syncthreads();
#pragma unroll
    for (int j = 0; j < 4; ++j) {
      const int f = kq + j * 4;
      const float4 a = *(const float4*)(feat + (size_t)(m0 + rl) * 256 + kk + f * 4);
      const float4 av = *(const float4*)(attv + b * 256 + kk + f * 4);
      As[f * 4 + 0][rl] = a.x * av.x;
      As[f * 4 + 1][rl] = a.y * av.y;
      As[f * 4 + 2][rl] = a.z * av.z;
      As[f * 4 + 3][rl] = a.w * av.w;
      const float4 bq = *(const float4*)(fw + (size_t)(o0 + rl) * 256 + kk + f * 4);
      Bs[f * 4 + 0][rl] = bq.x;
      Bs[f * 4 + 1][rl] = bq.y;
      Bs[f * 4 + 2][rl] = bq.z;
      Bs[f * 4 + 3][rl] = bq.w;
    }
    __syncthreads();
#pragma unroll 8
    for (int k = 0; k < 64; ++k) {
      const float4 a = *(const float4*)(&As[k][tm * 4]);
      const float4 bb = *(const float4*)(&Bs[k][tn * 4]);
      const float av[4] = {a.x, a.y, a.z, a.w};
      const float bv[4] = {bb.x, bb.y, bb.z, bb.w};
#pragma unroll
      for (int i = 0; i < 4; ++i)
#pragma unroll
        for (int j = 0; j < 4; ++j) acc[i][j] += av[i] * bv[j];
    }
  }
#pragma unroll
  for (int j = 0; j < 4; ++j) {
    const int o = o0 + tn * 4 + j;
    const float bias = fb[o];
    const float4 v = {acc[0][j] + bias, acc[1][j] + bias, acc[2][j] + bias,
                      acc[3][j] + bias};
    *(float4*)(out + (size_t)b * 524288 + (size_t)o * 4096 + hw0 + tm * 4) = v;
  }
}

extern "C" void kernel_launch(void* const* d_in, const int* in_sizes, int n_in,
                              void* d_out, int out_size, void* d_ws, size_t ws_size,
                              hipStream_t stream) {
  const float* x = (const float*)d_in[0];
  const float* w1 = (const float*)d_in[1];
  const float* w3 = (const float*)d_in[2];
  const float* b3 = (const float*)d_in[3];
  const float* lw = (const float*)d_in[4];
  const float* lb = (const float*)d_in[5];
  const float* ca1 = (const float*)d_in[6];
  const float* ca2 = (const float*)d_in[7];
  const float* fw = (const float*)d_in[8];
  const float* fb = (const float*)d_in[9];
  const float* binit = (const float*)d_in[10];

  float* ws = (float*)d_ws;
  float* bufA = ws;            // y -> xl -> feat   (M*256)
  float* bufB = ws + 4194304;  // xm                (M*256)
  float* psum = ws + 8388608;  // 4*64*256
  float* pmax = psum + 65536;
  float* attv = pmax + 65536;  // 1024
  float* out = (float*)d_out;
  float* out_att = out + 2097152;

  const dim3 blk(256);
  k_conv1x1<<<dim3(256, 4), blk, 0, stream>>>(x, w1, bufA);
  k_dwconv<<<dim3(4096), blk, 0, stream>>>(bufA, w3, b3, bufB);
  k_lower<<<dim3(256, 4), blk, 0, stream>>>(bufB, lw, lb, bufA);
  k_em_fast<<<dim3(4096), blk, 0, stream>>>(bufA, binit, bufB, bufA);
  k_em_slow<<<dim3(4096), blk, 0, stream>>>(bufA, binit, bufB, bufA);
  k_pool1<<<dim3(256), blk, 0, stream>>>(bufA, psum, pmax);
  k_att<<<dim3(4), blk, 0, stream>>>(psum, pmax, ca1, ca2, attv, out_att);
  k_fc<<<dim3(256, 2), blk, 0, stream>>>(bufA, attv, fw, fb, out);
}

// Round 4
// 118.793 us; speedup vs baseline: 2.8403x; 2.8403x over previous
//
#include <hip/hip_runtime.h>
#include <hip/hip_bf16.h>
#include <math.h>

#define EPS 1e-6f

// ---------------------------------------------------------------------------
// K1: y[m,p] = sum_c x[b,c,hw] * w1[p,c]     (m = b*4096 + hw)
// ---------------------------------------------------------------------------
__global__ __launch_bounds__(256) void k_conv1x1(const float* __restrict__ x,
                                                 const float* __restrict__ w1,
                                                 float* __restrict__ y) {
  __shared__ float As[64][68];  // [k(c)][m]
  __shared__ float Bs[64][68];  // [k(c)][p]
  const int t = threadIdx.x;
  const int m0 = blockIdx.x * 64, p0 = blockIdx.y * 64;
  const int b = m0 >> 12, hw0 = m0 & 4095;
  const int ml = t & 63, c0 = t >> 6;
  const int rl = t >> 2, kq = t & 3;
  const int tn = t & 15, tm = t >> 4;
  float acc[4][4] = {};
  for (int kk = 0; kk < 128; kk += 64) {
    __syncthreads();
#pragma unroll
    for (int i = 0; i < 16; ++i)
      As[c0 + i * 4][ml] = x[(size_t)(b * 128 + kk + c0 + i * 4) * 4096 + hw0 + ml];
#pragma unroll
    for (int j = 0; j < 4; ++j) {
      const int f = kq + j * 4;
      const float4 v = *(const float4*)(w1 + (size_t)(p0 + rl) * 128 + kk + f * 4);
      Bs[f * 4 + 0][rl] = v.x;
      Bs[f * 4 + 1][rl] = v.y;
      Bs[f * 4 + 2][rl] = v.z;
      Bs[f * 4 + 3][rl] = v.w;
    }
    __syncthreads();
#pragma unroll 8
    for (int k = 0; k < 64; ++k) {
      const float4 a = *(const float4*)(&As[k][tm * 4]);
      const float4 bb = *(const float4*)(&Bs[k][tn * 4]);
      const float av[4] = {a.x, a.y, a.z, a.w};
      const float bv[4] = {bb.x, bb.y, bb.z, bb.w};
#pragma unroll
      for (int i = 0; i < 4; ++i)
#pragma unroll
        for (int j = 0; j < 4; ++j) acc[i][j] += av[i] * bv[j];
    }
  }
#pragma unroll
  for (int i = 0; i < 4; ++i) {
    const float4 v = {acc[i][0], acc[i][1], acc[i][2], acc[i][3]};
    *(float4*)(y + (size_t)(m0 + tm * 4 + i) * 256 + p0 + tn * 4) = v;
  }
}

// ---------------------------------------------------------------------------
// K2: depthwise 3x3 SAME + bias, NHWC layout in/out.
// ---------------------------------------------------------------------------
__global__ __launch_bounds__(256) void k_dwconv(const float* __restrict__ y,
                                                const float* __restrict__ w3,
                                                const float* __restrict__ b3,
                                                float* __restrict__ xm) {
  __shared__ float wt[9][256];
  __shared__ float bs[256];
  const int t = threadIdx.x;
#pragma unroll
  for (int i = 0; i < 9; ++i) wt[i][t] = w3[t * 9 + i];
  bs[t] = b3[t];
  __syncthreads();
  const int sub = t >> 6;
  const int pq = t & 63;
  const int m = blockIdx.x * 4 + sub;
  const int hw = m & 4095;
  const int h = hw >> 6, w = hw & 63;
  const int bb = m >> 12;
  float4 acc = *(const float4*)(&bs[pq * 4]);
#pragma unroll
  for (int dy = -1; dy <= 1; ++dy) {
    const int hh = h + dy;
    if (hh < 0 || hh > 63) continue;
#pragma unroll
    for (int dx = -1; dx <= 1; ++dx) {
      const int ww = w + dx;
      if (ww < 0 || ww > 63) continue;
      const int idx = (dy + 1) * 3 + (dx + 1);
      const float4 v =
          *(const float4*)(y + (size_t)((bb << 12) + (hh << 6) + ww) * 256 + pq * 4);
      const float4 wv = *(const float4*)(&wt[idx][pq * 4]);
      acc.x += v.x * wv.x;
      acc.y += v.y * wv.y;
      acc.z += v.z * wv.z;
      acc.w += v.w * wv.w;
    }
  }
  *(float4*)(xm + (size_t)m * 256 + pq * 4) = acc;
}

// ---------------------------------------------------------------------------
// K3: xl = relu(xm @ lower_w^T + lb).
// ---------------------------------------------------------------------------
__global__ __launch_bounds__(256) void k_lower(const float* __restrict__ xm,
                                               const float* __restrict__ lw,
                                               const float* __restrict__ lb,
                                               float* __restrict__ xl) {
  __shared__ float As[64][68];
  __shared__ float Bs[64][68];
  const int t = threadIdx.x;
  const int m0 = blockIdx.x * 64, n0 = blockIdx.y * 64;
  const int rl = t >> 2, kq = t & 3;
  const int tn = t & 15, tm = t >> 4;
  float acc[4][4] = {};
  for (int kk = 0; kk < 256; kk += 64) {
    __syncthreads();
#pragma unroll
    for (int j = 0; j < 4; ++j) {
      const int f = kq + j * 4;
      const float4 a = *(const float4*)(xm + (size_t)(m0 + rl) * 256 + kk + f * 4);
      As[f * 4 + 0][rl] = a.x;
      As[f * 4 + 1][rl] = a.y;
      As[f * 4 + 2][rl] = a.z;
      As[f * 4 + 3][rl] = a.w;
      const float4 bq = *(const float4*)(lw + (size_t)(n0 + rl) * 256 + kk + f * 4);
      Bs[f * 4 + 0][rl] = bq.x;
      Bs[f * 4 + 1][rl] = bq.y;
      Bs[f * 4 + 2][rl] = bq.z;
      Bs[f * 4 + 3][rl] = bq.w;
    }
    __syncthreads();
#pragma unroll 8
    for (int k = 0; k < 64; ++k) {
      const float4 a = *(const float4*)(&As[k][tm * 4]);
      const float4 bb = *(const float4*)(&Bs[k][tn * 4]);
      const float av[4] = {a.x, a.y, a.z, a.w};
      const float bv[4] = {bb.x, bb.y, bb.z, bb.w};
#pragma unroll
      for (int i = 0; i < 4; ++i)
#pragma unroll
        for (int j = 0; j < 4; ++j) acc[i][j] += av[i] * bv[j];
    }
  }
  const float4 bias4 = *(const float4*)(lb + n0 + tn * 4);
  const float bias[4] = {bias4.x, bias4.y, bias4.z, bias4.w};
#pragma unroll
  for (int i = 0; i < 4; ++i) {
    float4 v;
    v.x = fmaxf(acc[i][0] + bias[0], 0.f);
    v.y = fmaxf(acc[i][1] + bias[1], 0.f);
    v.z = fmaxf(acc[i][2] + bias[2], 0.f);
    v.w = fmaxf(acc[i][3] + bias[3], 0.f);
    *(float4*)(xl + (size_t)(m0 + tm * 4 + i) * 256 + n0 + tn * 4) = v;
  }
}

// ---------------------------------------------------------------------------
// K4a: fast EM path. The NORMALIZED bases b = v/max(|v|,1e-12) equal exactly
// 1.0f whenever v >= 1e-12 (uniform [0,1) draws: ~always). Then all 16 r
// columns stay bitwise identical through all iterations and EM collapses to
// scalar recurrences per pixel row:
//   C' = C*s*B / (16*C*B^2 + eps);  B' = B*num/(den+eps),
//   num = sum_n s*C', den = 16*B*sum_n C'^2;  xr = 16*B*C''.
// Gate is on the NORMALIZED value (round-3 bug: gated on raw binit).
// ---------------------------------------------------------------------------
__global__ __launch_bounds__(256) void k_em_fast(const float* xl,
                                                 const float* __restrict__ binit,
                                                 const float* __restrict__ xmp,
                                                 float* feat) {
  const int lane = threadIdx.x & 63;
  const int m = blockIdx.x * 4 + (threadIdx.x >> 6);
  const float bv0 = binit[m * 16 + (lane & 15)];
  const float bn0 = bv0 / fmaxf(fabsf(bv0), 1e-12f);
  if (!__all(bn0 == 1.0f)) return;  // asymmetric pixel -> slow kernel
  const float4 s4 = *(const float4*)(xl + (size_t)m * 256 + lane * 4);
  const float s[4] = {s4.x, s4.y, s4.z, s4.w};
  float C[4] = {0.0625f, 0.0625f, 0.0625f, 0.0625f};
  float Bv = 1.f;
  for (int step = 0; step < 6; ++step) {
    const float k1 = 16.f * Bv * Bv;
    float pnum = 0.f, psq = 0.f;
#pragma unroll
    for (int i = 0; i < 4; ++i) {
      const float den = fmaf(C[i], k1, EPS);
      const float cn = C[i] * (s[i] * Bv) * __builtin_amdgcn_rcpf(den);
      C[i] = cn;
      pnum = fmaf(s[i], cn, pnum);
      psq = fmaf(cn, cn, psq);
    }
#pragma unroll
    for (int d = 1; d < 64; d <<= 1) {
      pnum += __shfl_xor(pnum, d, 64);
      psq += __shfl_xor(psq, d, 64);
    }
    const float den2 = fmaf(16.f * Bv, psq, EPS);
    Bv = Bv * pnum * __builtin_amdgcn_rcpf(den2);
  }
  const float4 xm4 = *(const float4*)(xmp + (size_t)m * 256 + lane * 4);
  const float xmv[4] = {xm4.x, xm4.y, xm4.z, xm4.w};
  const float k1 = 16.f * Bv * Bv;
  float o[4];
#pragma unroll
  for (int i = 0; i < 4; ++i) {
    const float den = fmaf(C[i], k1, EPS);
    const float cn = C[i] * (s[i] * Bv) * __builtin_amdgcn_rcpf(den);
    const float xr = 16.f * Bv * cn;
    o[i] = fmaxf(xmv[i] + xr, 0.f);
  }
  const float4 outv = {o[0], o[1], o[2], o[3]};
  *(float4*)(feat + (size_t)m * 256 + lane * 4) = outv;
}

// ---------------------------------------------------------------------------
// K4b: general EM fallback for pixels whose NORMALIZED bases are not all 1.0
// (exact-zero uniform draws etc.). Early-exits for symmetric pixels.
// ---------------------------------------------------------------------------
__global__ __launch_bounds__(256, 2) void k_em_slow(const float* xl,
                                                    const float* __restrict__ binit,
                                                    const float* __restrict__ xmp,
                                                    float* feat) {
  const int lane = threadIdx.x & 63;
  const int m = blockIdx.x * 4 + (threadIdx.x >> 6);
  const float bv0 = binit[m * 16 + (lane & 15)];
  const float bn0 = bv0 / fmaxf(fabsf(bv0), 1e-12f);
  if (__all(bn0 == 1.0f)) return;  // handled by fast kernel
  const float4 s4 = *(const float4*)(xl + (size_t)m * 256 + lane * 4);
  const float s[4] = {s4.x, s4.y, s4.z, s4.w};
  float b[16];
#pragma unroll
  for (int r = 0; r < 16; ++r) {
    const float v = binit[m * 16 + r];
    b[r] = v / fmaxf(fabsf(v), 1e-12f);
  }
  float c[4][16];
#pragma unroll
  for (int i = 0; i < 4; ++i) {
    float mx = s[i] * b[0];
#pragma unroll
    for (int r = 1; r < 16; ++r) mx = fmaxf(mx, s[i] * b[r]);
    float sum = 0.f;
#pragma unroll
    for (int r = 0; r < 16; ++r) {
      const float e = __expf(s[i] * b[r] - mx);
      c[i][r] = e;
      sum += e;
    }
    const float inv = __fdividef(1.f, sum);
#pragma unroll
    for (int r = 0; r < 16; ++r) c[i][r] *= inv;
  }
  for (int step = 0; step < 6; ++step) {
    float red[32];
#pragma unroll
    for (int r = 0; r < 32; ++r) red[r] = 0.f;
#pragma unroll
    for (int i = 0; i < 4; ++i) {
      float tt = 0.f;
#pragma unroll
      for (int r = 0; r < 16; ++r) tt += c[i][r] * b[r];
      float tp = 0.f;
#pragma unroll
      for (int r = 0; r < 16; ++r) {
        const float cn = c[i][r] * (s[i] * b[r]) * __frcp_rn(tt * b[r] + EPS);
        c[i][r] = cn;
        tp += cn * b[r];
        red[r] += s[i] * cn;
      }
#pragma unroll
      for (int r = 0; r < 16; ++r) red[16 + r] += tp * c[i][r];
    }
    int cnt = 32;
#pragma unroll
    for (int k = 4; k >= 0; --k) {
      const int d = 1 << k;
      const bool up = (lane >> k) & 1;
      const int half = cnt >> 1;
#pragma unroll
      for (int j = 0; j < half; ++j) {
        const float lo = red[j], hi = red[j + half];
        const float send = up ? lo : hi;
        const float recv = __shfl_xor(send, d, 64);
        red[j] = (up ? hi : lo) + recv;
      }
      cnt = half;
    }
    float S = red[0] + __shfl_xor(red[0], 32, 64);
    const float dpart = __shfl_xor(S, 16, 64);
    const float q = S * __frcp_rn(dpart + EPS);
#pragma unroll
    for (int r = 0; r < 16; ++r) b[r] *= __shfl(q, r, 64);
  }
  const float4 xm4 = *(const float4*)(xmp + (size_t)m * 256 + lane * 4);
  const float xmv[4] = {xm4.x, xm4.y, xm4.z, xm4.w};
  float o4[4];
#pragma unroll
  for (int i = 0; i < 4; ++i) {
    float tt = 0.f;
#pragma unroll
    for (int r = 0; r < 16; ++r) tt += c[i][r] * b[r];
    float xr = 0.f;
#pragma unroll
    for (int r = 0; r < 16; ++r) {
      const float cn = c[i][r] * (s[i] * b[r]) * __frcp_rn(tt * b[r] + EPS);
      xr += b[r] * cn;
    }
    o4[i] = fmaxf(xmv[i] + xr, 0.f);
  }
  const float4 outv = {o4[0], o4[1], o4[2], o4[3]};
  *(float4*)(feat + (size_t)m * 256 + lane * 4) = outv;
}

// ---------------------------------------------------------------------------
// K5: pooling phase 1
// ---------------------------------------------------------------------------
__global__ __launch_bounds__(256) void k_pool1(const float* __restrict__ feat,
                                               float* __restrict__ psum,
                                               float* __restrict__ pmax) {
  const int t = threadIdx.x;
  const int b = blockIdx.x >> 6;
  const int ch = blockIdx.x & 63;
  const float* fp = feat + (size_t)(b * 4096 + ch * 64) * 256 + t;
  float sum = 0.f, mx = -1e30f;
#pragma unroll 8
  for (int r = 0; r < 64; ++r) {
    const float v = fp[(size_t)r * 256];
    sum += v;
    mx = fmaxf(mx, v);
  }
  psum[(size_t)blockIdx.x * 256 + t] = sum;
  pmax[(size_t)blockIdx.x * 256 + t] = mx;
}

// ---------------------------------------------------------------------------
// K6: finish pooling + channel-attention MLP + sigmoid
// ---------------------------------------------------------------------------
__global__ __launch_bounds__(256) void k_att(const float* __restrict__ psum,
                                             const float* __restrict__ pmax,
                                             const float* __restrict__ ca1,
                                             const float* __restrict__ ca2,
                                             float* __restrict__ attv,
                                             float* __restrict__ out_att) {
  __shared__ float sA[256], sM[256], sH[64];
  const int t = threadIdx.x;
  const int b = blockIdx.x;
  float sum = 0.f, mx = -1e30f;
#pragma unroll 8
  for (int ch = 0; ch < 64; ++ch) {
    sum += psum[(size_t)(b * 64 + ch) * 256 + t];
    mx = fmaxf(mx, pmax[(size_t)(b * 64 + ch) * 256 + t]);
  }
  sA[t] = sum * (1.0f / 4096.0f);
  sM[t] = mx;
  __syncthreads();
  if (t < 64) {
    float ha = 0.f, hm = 0.f;
#pragma unroll 8
    for (int p = 0; p < 256; ++p) {
      const float w = ca1[t * 256 + p];
      ha += sA[p] * w;
      hm += sM[p] * w;
    }
    sH[t] = fmaxf(ha, 0.f) + fmaxf(hm, 0.f);
  }
  __syncthreads();
  float logit = 0.f;
#pragma unroll 8
  for (int a = 0; a < 64; ++a) logit += sH[a] * ca2[t * 64 + a];
  const float av = 1.0f / (1.0f + expf(-logit));
  attv[b * 256 + t] = av;
  out_att[b * 256 + t] = av;
}

// ---------------------------------------------------------------------------
// K7: out[b,o,hw] = sum_p feat[m,p]*att[b,p]*fc_w[o,p] + fc_b[o]
// ---------------------------------------------------------------------------
__global__ __launch_bounds__(256) void k_fc(const float* __restrict__ feat,
                                            const float* __restrict__ attv,
                                            const float* __restrict__ fw,
                                            const float* __restrict__ fb,
                                            float* __restrict__ out) {
  __shared__ float As[64][68];
  __shared__ float Bs[64][68];
  const int t = threadIdx.x;
  const int m0 = blockIdx.x * 64, o0 = blockIdx.y * 64;
  const int b = m0 >> 12, hw0 = m0 & 4095;
  const int rl = t >> 2, kq = t & 3;
  const int tm = t & 15, tn = t >> 4;
  float acc[4][4] = {};
  for (int kk = 0; kk < 256; kk += 64) {
    __syncthreads();
#pragma unroll
    for (int j = 0; j < 4; ++j) {
      const int f = kq + j * 4;
      const float4 a = *(const float4*)(feat + (size_t)(m0 + rl) * 256 + kk + f * 4);
      const float4 av = *(const float4*)(attv + b * 256 + kk + f * 4);
      As[f * 4 + 0][rl] = a.x * av.x;
      As[f * 4 + 1][rl] = a.y * av.y;
      As[f * 4 + 2][rl] = a.z * av.z;
      As[f * 4 + 3][rl] = a.w * av.w;
      const float4 bq = *(const float4*)(fw + (size_t)(o0 + rl) * 256 + kk + f * 4);
      Bs[f * 4 + 0][rl] = bq.x;
      Bs[f * 4 + 1][rl] = bq.y;
      Bs[f * 4 + 2][rl] = bq.z;
      Bs[f * 4 + 3][rl] = bq.w;
    }
    __syncthreads();
#pragma unroll 8
    for (int k = 0; k < 64; ++k) {
      const float4 a = *(const float4*)(&As[k][tm * 4]);
      const float4 bb = *(const float4*)(&Bs[k][tn * 4]);
      const float av[4] = {a.x, a.y, a.z, a.w};
      const float bv[4] = {bb.x, bb.y, bb.z, bb.w};
#pragma unroll
      for (int i = 0; i < 4; ++i)
#pragma unroll
        for (int j = 0; j < 4; ++j) acc[i][j] += av[i] * bv[j];
    }
  }
#pragma unroll
  for (int j = 0; j < 4; ++j) {
    const int o = o0 + tn * 4 + j;
    const float bias = fb[o];
    const float4 v = {acc[0][j] + bias, acc[1][j] + bias, acc[2][j] + bias,
                      acc[3][j] + bias};
    *(float4*)(out + (size_t)b * 524288 + (size_t)o * 4096 + hw0 + tm * 4) = v;
  }
}

extern "C" void kernel_launch(void* const* d_in, const int* in_sizes, int n_in,
                              void* d_out, int out_size, void* d_ws, size_t ws_size,
                              hipStream_t stream) {
  const float* x = (const float*)d_in[0];
  const float* w1 = (const float*)d_in[1];
  const float* w3 = (const float*)d_in[2];
  const float* b3 = (const float*)d_in[3];
  const float* lw = (const float*)d_in[4];
  const float* lb = (const float*)d_in[5];
  const float* ca1 = (const float*)d_in[6];
  const float* ca2 = (const float*)d_in[7];
  const float* fw = (const float*)d_in[8];
  const float* fb = (const float*)d_in[9];
  const float* binit = (const float*)d_in[10];

  float* ws = (float*)d_ws;
  float* bufA = ws;            // y -> xl -> feat   (M*256)
  float* bufB = ws + 4194304;  // xm                (M*256)
  float* psum = ws + 8388608;  // 4*64*256
  float* pmax = psum + 65536;
  float* attv = pmax + 65536;  // 1024
  float* out = (float*)d_out;
  float* out_att = out + 2097152;

  const dim3 blk(256);
  k_conv1x1<<<dim3(256, 4), blk, 0, stream>>>(x, w1, bufA);
  k_dwconv<<<dim3(4096), blk, 0, stream>>>(bufA, w3, b3, bufB);
  k_lower<<<dim3(256, 4), blk, 0, stream>>>(bufB, lw, lb, bufA);
  k_em_fast<<<dim3(4096), blk, 0, stream>>>(bufA, binit, bufB, bufA);
  k_em_slow<<<dim3(4096), blk, 0, stream>>>(bufA, binit, bufB, bufA);
  k_pool1<<<dim3(256), blk, 0, stream>>>(bufA, psum, pmax);
  k_att<<<dim3(4), blk, 0, stream>>>(psum, pmax, ca1, ca2, attv, out_att);
  k_fc<<<dim3(256, 2), blk, 0, stream>>>(bufA, attv, fw, fb, out);
}

// Round 5
// 94.553 us; speedup vs baseline: 3.5685x; 1.2564x over previous
//
#include <hip/hip_runtime.h>
#include <hip/hip_bf16.h>
#include <math.h>

#define EPS 1e-6f
#define PITCH 72  // bf16 elems per LDS row: 64 K + 8 pad (2-way bank conflict = free)

typedef short s16x8 __attribute__((ext_vector_type(8)));
typedef float f32x4 __attribute__((ext_vector_type(4)));

__device__ __forceinline__ short bf16of(float f) {
  __hip_bfloat16 h = __float2bfloat16(f);
  return __builtin_bit_cast(short, h);
}

// ---------------------------------------------------------------------------
// K1 (MFMA): y[m][p] = sum_c x[img][c][hw] * w1[p][c].
// MFMA-M = p (256, full), MFMA-N = m (64/block), K = 128 (BK=64, 2 iters).
// C frag: col(lane&15)=m, row((lane>>4)*4+reg)=p -> float4 store contiguous in p.
// ---------------------------------------------------------------------------
__global__ __launch_bounds__(256) void k_conv1x1(const float* __restrict__ x,
                                                 const float* __restrict__ w1,
                                                 float* __restrict__ y) {
  __shared__ __align__(16) short Aw[256 * PITCH];  // [p][k]
  __shared__ __align__(16) short Xs[64 * PITCH];   // [m][k]
  const int t = threadIdx.x;
  const int m0 = blockIdx.x * 64;
  const int img = m0 >> 12, hw0 = m0 & 4095;
  const int lane = t & 63, w = t >> 6;
  const int lrow = lane & 15, lk = (lane >> 4) * 8;
  f32x4 acc[8][2];
#pragma unroll
  for (int i = 0; i < 8; ++i)
#pragma unroll
    for (int j = 0; j < 2; ++j) acc[i][j] = {0.f, 0.f, 0.f, 0.f};

  for (int kk = 0; kk < 128; kk += 64) {
    __syncthreads();
    {  // stage w1: row p = t, 64 k
      const float* wp = w1 + (size_t)t * 128 + kk;
#pragma unroll
      for (int q = 0; q < 16; ++q) {
        const float4 v = *(const float4*)(wp + q * 4);
        short4 sv = {bf16of(v.x), bf16of(v.y), bf16of(v.z), bf16of(v.w)};
        *(short4*)(&Aw[t * PITCH + q * 4]) = sv;
      }
    }
    {  // stage x (c-major) -> Xs[m][c]: 4x4 register transpose
      const int m4 = (t & 15) * 4;
      const int cg = (t >> 4) * 4;  // 0..60
      float4 col[4];
#pragma unroll
      for (int cc = 0; cc < 4; ++cc)
        col[cc] = *(const float4*)(x + (size_t)(img * 128 + kk + cg + cc) * 4096 + hw0 + m4);
#pragma unroll
      for (int r = 0; r < 4; ++r) {
        short4 sv = {bf16of(((const float*)&col[0])[r]),
                     bf16of(((const float*)&col[1])[r]),
                     bf16of(((const float*)&col[2])[r]),
                     bf16of(((const float*)&col[3])[r])};
        *(short4*)(&Xs[(m4 + r) * PITCH + cg]) = sv;
      }
    }
    __syncthreads();
#pragma unroll
    for (int ks = 0; ks < 2; ++ks) {
      const int ko = ks * 32 + lk;
      s16x8 bfr[2];
#pragma unroll
      for (int j = 0; j < 2; ++j)
        bfr[j] = *(const s16x8*)(&Xs[(((w >> 1) * 2 + j) * 16 + lrow) * PITCH + ko]);
#pragma unroll
      for (int i = 0; i < 8; ++i) {
        const s16x8 af = *(const s16x8*)(&Aw[(((w & 1) * 8 + i) * 16 + lrow) * PITCH + ko]);
#pragma unroll
        for (int j = 0; j < 2; ++j)
          acc[i][j] = __builtin_amdgcn_mfma_f32_16x16x32_bf16(af, bfr[j], acc[i][j], 0, 0, 0);
      }
    }
  }
#pragma unroll
  for (int i = 0; i < 8; ++i) {
    const int p = ((w & 1) * 8 + i) * 16 + (lane >> 4) * 4;
#pragma unroll
    for (int j = 0; j < 2; ++j) {
      const int m = m0 + ((w >> 1) * 2 + j) * 16 + lrow;
      *(f32x4*)(y + (size_t)m * 256 + p) = acc[i][j];
    }
  }
}

// ---------------------------------------------------------------------------
// K2: depthwise 3x3 SAME + bias, NHWC layout in/out (unchanged).
// ---------------------------------------------------------------------------
__global__ __launch_bounds__(256) void k_dwconv(const float* __restrict__ y,
                                                const float* __restrict__ w3,
                                                const float* __restrict__ b3,
                                                float* __restrict__ xm) {
  __shared__ float wt[9][256];
  __shared__ float bs[256];
  const int t = threadIdx.x;
#pragma unroll
  for (int i = 0; i < 9; ++i) wt[i][t] = w3[t * 9 + i];
  bs[t] = b3[t];
  __syncthreads();
  const int sub = t >> 6;
  const int pq = t & 63;
  const int m = blockIdx.x * 4 + sub;
  const int hw = m & 4095;
  const int h = hw >> 6, ww = hw & 63;
  const int bb = m >> 12;
  float4 acc = *(const float4*)(&bs[pq * 4]);
#pragma unroll
  for (int dy = -1; dy <= 1; ++dy) {
    const int hh = h + dy;
    if (hh < 0 || hh > 63) continue;
#pragma unroll
    for (int dx = -1; dx <= 1; ++dx) {
      const int w2 = ww + dx;
      if (w2 < 0 || w2 > 63) continue;
      const int idx = (dy + 1) * 3 + (dx + 1);
      const float4 v =
          *(const float4*)(y + (size_t)((bb << 12) + (hh << 6) + w2) * 256 + pq * 4);
      const float4 wv = *(const float4*)(&wt[idx][pq * 4]);
      acc.x += v.x * wv.x;
      acc.y += v.y * wv.y;
      acc.z += v.z * wv.z;
      acc.w += v.w * wv.w;
    }
  }
  *(float4*)(xm + (size_t)m * 256 + pq * 4) = acc;
}

// ---------------------------------------------------------------------------
// K3 (MFMA): xl[m][n] = relu(sum_k xm[m][k]*lw[n][k] + lb[n]).
// MFMA-M = n (256, full), N = m (64/block), K = 256 (4 iters).
// ---------------------------------------------------------------------------
__global__ __launch_bounds__(256) void k_lower(const float* __restrict__ xm,
                                               const float* __restrict__ lw,
                                               const float* __restrict__ lb,
                                               float* __restrict__ xl) {
  __shared__ __align__(16) short Aw[256 * PITCH];  // [n][k]
  __shared__ __align__(16) short Xs[64 * PITCH];   // [m][k]
  const int t = threadIdx.x;
  const int m0 = blockIdx.x * 64;
  const int lane = t & 63, w = t >> 6;
  const int lrow = lane & 15, lk = (lane >> 4) * 8;
  f32x4 acc[8][2];
#pragma unroll
  for (int i = 0; i < 8; ++i)
#pragma unroll
    for (int j = 0; j < 2; ++j) acc[i][j] = {0.f, 0.f, 0.f, 0.f};

  for (int kk = 0; kk < 256; kk += 64) {
    __syncthreads();
    {  // stage lw: row n = t
      const float* wp = lw + (size_t)t * 256 + kk;
#pragma unroll
      for (int q = 0; q < 16; ++q) {
        const float4 v = *(const float4*)(wp + q * 4);
        short4 sv = {bf16of(v.x), bf16of(v.y), bf16of(v.z), bf16of(v.w)};
        *(short4*)(&Aw[t * PITCH + q * 4]) = sv;
      }
    }
    {  // stage xm (k-contiguous): m = t&63, q = t>>6
      const int m = t & 63, q = t >> 6;
      const float* xp = xm + (size_t)(m0 + m) * 256 + kk + q * 16;
#pragma unroll
      for (int jj = 0; jj < 4; ++jj) {
        const float4 v = *(const float4*)(xp + jj * 4);
        short4 sv = {bf16of(v.x), bf16of(v.y), bf16of(v.z), bf16of(v.w)};
        *(short4*)(&Xs[m * PITCH + q * 16 + jj * 4]) = sv;
      }
    }
    __syncthreads();
#pragma unroll
    for (int ks = 0; ks < 2; ++ks) {
      const int ko = ks * 32 + lk;
      s16x8 bfr[2];
#pragma unroll
      for (int j = 0; j < 2; ++j)
        bfr[j] = *(const s16x8*)(&Xs[(((w >> 1) * 2 + j) * 16 + lrow) * PITCH + ko]);
#pragma unroll
      for (int i = 0; i < 8; ++i) {
        const s16x8 af = *(const s16x8*)(&Aw[(((w & 1) * 8 + i) * 16 + lrow) * PITCH + ko]);
#pragma unroll
        for (int j = 0; j < 2; ++j)
          acc[i][j] = __builtin_amdgcn_mfma_f32_16x16x32_bf16(af, bfr[j], acc[i][j], 0, 0, 0);
      }
    }
  }
#pragma unroll
  for (int i = 0; i < 8; ++i) {
    const int n = ((w & 1) * 8 + i) * 16 + (lane >> 4) * 4;
    const float4 bias = *(const float4*)(lb + n);
#pragma unroll
    for (int j = 0; j < 2; ++j) {
      const int m = m0 + ((w >> 1) * 2 + j) * 16 + lrow;
      f32x4 v = acc[i][j];
      v.x = fmaxf(v.x + bias.x, 0.f);
      v.y = fmaxf(v.y + bias.y, 0.f);
      v.z = fmaxf(v.z + bias.z, 0.f);
      v.w = fmaxf(v.w + bias.w, 0.f);
      *(f32x4*)(xl + (size_t)m * 256 + n) = v;
    }
  }
}

// ---------------------------------------------------------------------------
// K4a: fast EM path (symmetric bases; validated round 4).
// ---------------------------------------------------------------------------
__global__ __launch_bounds__(256) void k_em_fast(const float* xl,
                                                 const float* __restrict__ binit,
                                                 const float* __restrict__ xmp,
                                                 float* feat) {
  const int lane = threadIdx.x & 63;
  const int m = blockIdx.x * 4 + (threadIdx.x >> 6);
  const float bv0 = binit[m * 16 + (lane & 15)];
  const float bn0 = bv0 / fmaxf(fabsf(bv0), 1e-12f);
  if (!__all(bn0 == 1.0f)) return;
  const float4 s4 = *(const float4*)(xl + (size_t)m * 256 + lane * 4);
  const float s[4] = {s4.x, s4.y, s4.z, s4.w};
  float C[4] = {0.0625f, 0.0625f, 0.0625f, 0.0625f};
  float Bv = 1.f;
  for (int step = 0; step < 6; ++step) {
    const float k1 = 16.f * Bv * Bv;
    float pnum = 0.f, psq = 0.f;
#pragma unroll
    for (int i = 0; i < 4; ++i) {
      const float den = fmaf(C[i], k1, EPS);
      const float cn = C[i] * (s[i] * Bv) * __builtin_amdgcn_rcpf(den);
      C[i] = cn;
      pnum = fmaf(s[i], cn, pnum);
      psq = fmaf(cn, cn, psq);
    }
#pragma unroll
    for (int d = 1; d < 64; d <<= 1) {
      pnum += __shfl_xor(pnum, d, 64);
      psq += __shfl_xor(psq, d, 64);
    }
    const float den2 = fmaf(16.f * Bv, psq, EPS);
    Bv = Bv * pnum * __builtin_amdgcn_rcpf(den2);
  }
  const float4 xm4 = *(const float4*)(xmp + (size_t)m * 256 + lane * 4);
  const float xmv[4] = {xm4.x, xm4.y, xm4.z, xm4.w};
  const float k1 = 16.f * Bv * Bv;
  float o[4];
#pragma unroll
  for (int i = 0; i < 4; ++i) {
    const float den = fmaf(C[i], k1, EPS);
    const float cn = C[i] * (s[i] * Bv) * __builtin_amdgcn_rcpf(den);
    const float xr = 16.f * Bv * cn;
    o[i] = fmaxf(xmv[i] + xr, 0.f);
  }
  const float4 outv = {o[0], o[1], o[2], o[3]};
  *(float4*)(feat + (size_t)m * 256 + lane * 4) = outv;
}

// ---------------------------------------------------------------------------
// K4b: general EM fallback (early-exits for symmetric pixels).
// ---------------------------------------------------------------------------
__global__ __launch_bounds__(256, 2) void k_em_slow(const float* xl,
                                                    const float* __restrict__ binit,
                                                    const float* __restrict__ xmp,
                                                    float* feat) {
  const int lane = threadIdx.x & 63;
  const int m = blockIdx.x * 4 + (threadIdx.x >> 6);
  const float bv0 = binit[m * 16 + (lane & 15)];
  const float bn0 = bv0 / fmaxf(fabsf(bv0), 1e-12f);
  if (__all(bn0 == 1.0f)) return;
  const float4 s4 = *(const float4*)(xl + (size_t)m * 256 + lane * 4);
  const float s[4] = {s4.x, s4.y, s4.z, s4.w};
  float b[16];
#pragma unroll
  for (int r = 0; r < 16; ++r) {
    const float v = binit[m * 16 + r];
    b[r] = v / fmaxf(fabsf(v), 1e-12f);
  }
  float c[4][16];
#pragma unroll
  for (int i = 0; i < 4; ++i) {
    float mx = s[i] * b[0];
#pragma unroll
    for (int r = 1; r < 16; ++r) mx = fmaxf(mx, s[i] * b[r]);
    float sum = 0.f;
#pragma unroll
    for (int r = 0; r < 16; ++r) {
      const float e = __expf(s[i] * b[r] - mx);
      c[i][r] = e;
      sum += e;
    }
    const float inv = __fdividef(1.f, sum);
#pragma unroll
    for (int r = 0; r < 16; ++r) c[i][r] *= inv;
  }
  for (int step = 0; step < 6; ++step) {
    float red[32];
#pragma unroll
    for (int r = 0; r < 32; ++r) red[r] = 0.f;
#pragma unroll
    for (int i = 0; i < 4; ++i) {
      float tt = 0.f;
#pragma unroll
      for (int r = 0; r < 16; ++r) tt += c[i][r] * b[r];
      float tp = 0.f;
#pragma unroll
      for (int r = 0; r < 16; ++r) {
        const float cn = c[i][r] * (s[i] * b[r]) * __frcp_rn(tt * b[r] + EPS);
        c[i][r] = cn;
        tp += cn * b[r];
        red[r] += s[i] * cn;
      }
#pragma unroll
      for (int r = 0; r < 16; ++r) red[16 + r] += tp * c[i][r];
    }
    int cnt = 32;
#pragma unroll
    for (int k = 4; k >= 0; --k) {
      const int d = 1 << k;
      const bool up = (lane >> k) & 1;
      const int half = cnt >> 1;
#pragma unroll
      for (int j = 0; j < half; ++j) {
        const float lo = red[j], hi = red[j + half];
        const float send = up ? lo : hi;
        const float recv = __shfl_xor(send, d, 64);
        red[j] = (up ? hi : lo) + recv;
      }
      cnt = half;
    }
    float S = red[0] + __shfl_xor(red[0], 32, 64);
    const float dpart = __shfl_xor(S, 16, 64);
    const float q = S * __frcp_rn(dpart + EPS);
#pragma unroll
    for (int r = 0; r < 16; ++r) b[r] *= __shfl(q, r, 64);
  }
  const float4 xm4 = *(const float4*)(xmp + (size_t)m * 256 + lane * 4);
  const float xmv[4] = {xm4.x, xm4.y, xm4.z, xm4.w};
  float o4[4];
#pragma unroll
  for (int i = 0; i < 4; ++i) {
    float tt = 0.f;
#pragma unroll
    for (int r = 0; r < 16; ++r) tt += c[i][r] * b[r];
    float xr = 0.f;
#pragma unroll
    for (int r = 0; r < 16; ++r) {
      const float cn = c[i][r] * (s[i] * b[r]) * __frcp_rn(tt * b[r] + EPS);
      xr += b[r] * cn;
    }
    o4[i] = fmaxf(xmv[i] + xr, 0.f);
  }
  const float4 outv = {o4[0], o4[1], o4[2], o4[3]};
  *(float4*)(feat + (size_t)m * 256 + lane * 4) = outv;
}

// ---------------------------------------------------------------------------
// K5: pooling phase 1 (unchanged).
// ---------------------------------------------------------------------------
__global__ __launch_bounds__(256) void k_pool1(const float* __restrict__ feat,
                                               float* __restrict__ psum,
                                               float* __restrict__ pmax) {
  const int t = threadIdx.x;
  const int b = blockIdx.x >> 6;
  const int ch = blockIdx.x & 63;
  const float* fp = feat + (size_t)(b * 4096 + ch * 64) * 256 + t;
  float sum = 0.f, mx = -1e30f;
#pragma unroll 8
  for (int r = 0; r < 64; ++r) {
    const float v = fp[(size_t)r * 256];
    sum += v;
    mx = fmaxf(mx, v);
  }
  psum[(size_t)blockIdx.x * 256 + t] = sum;
  pmax[(size_t)blockIdx.x * 256 + t] = mx;
}

// ---------------------------------------------------------------------------
// K6: finish pooling + channel-attention MLP + sigmoid (unchanged).
// ---------------------------------------------------------------------------
__global__ __launch_bounds__(256) void k_att(const float* __restrict__ psum,
                                             const float* __restrict__ pmax,
                                             const float* __restrict__ ca1,
                                             const float* __restrict__ ca2,
                                             float* __restrict__ attv,
                                             float* __restrict__ out_att) {
  __shared__ float sA[256], sM[256], sH[64];
  const int t = threadIdx.x;
  const int b = blockIdx.x;
  float sum = 0.f, mx = -1e30f;
#pragma unroll 8
  for (int ch = 0; ch < 64; ++ch) {
    sum += psum[(size_t)(b * 64 + ch) * 256 + t];
    mx = fmaxf(mx, pmax[(size_t)(b * 64 + ch) * 256 + t]);
  }
  sA[t] = sum * (1.0f / 4096.0f);
  sM[t] = mx;
  __syncthreads();
  if (t < 64) {
    float ha = 0.f, hm = 0.f;
#pragma unroll 8
    for (int p = 0; p < 256; ++p) {
      const float w = ca1[t * 256 + p];
      ha += sA[p] * w;
      hm += sM[p] * w;
    }
    sH[t] = fmaxf(ha, 0.f) + fmaxf(hm, 0.f);
  }
  __syncthreads();
  float logit = 0.f;
#pragma unroll 8
  for (int a = 0; a < 64; ++a) logit += sH[a] * ca2[t * 64 + a];
  const float av = 1.0f / (1.0f + expf(-logit));
  attv[b * 256 + t] = av;
  out_att[b * 256 + t] = av;
}

// ---------------------------------------------------------------------------
// K7 (MFMA): out[img][o][hw] = sum_k feat[m][k]*att[img][k]*fw[o][k] + fb[o].
// MFMA-M = m (64/block, rows -> hw-contiguous float4 stores), N = o (128, full).
// ---------------------------------------------------------------------------
__global__ __launch_bounds__(256) void k_fc(const float* __restrict__ feat,
                                            const float* __restrict__ attv,
                                            const float* __restrict__ fw,
                                            const float* __restrict__ fb,
                                            float* __restrict__ out) {
  __shared__ __align__(16) short Fs[64 * PITCH];   // [m][k]
  __shared__ __align__(16) short Ws[128 * PITCH];  // [o][k]
  const int t = threadIdx.x;
  const int m0 = blockIdx.x * 64;
  const int img = m0 >> 12, hw0 = m0 & 4095;
  const int lane = t & 63, w = t >> 6;
  const int lrow = lane & 15, lk = (lane >> 4) * 8;
  f32x4 acc[2][4];  // [m-frag][o-frag]
#pragma unroll
  for (int i = 0; i < 2; ++i)
#pragma unroll
    for (int j = 0; j < 4; ++j) acc[i][j] = {0.f, 0.f, 0.f, 0.f};

  for (int kk = 0; kk < 256; kk += 64) {
    __syncthreads();
    {  // stage feat * att
      const int m = t & 63, q = t >> 6;
      const float* fp = feat + (size_t)(m0 + m) * 256 + kk + q * 16;
      const float* ap = attv + img * 256 + kk + q * 16;
#pragma unroll
      for (int jj = 0; jj < 4; ++jj) {
        const float4 v = *(const float4*)(fp + jj * 4);
        const float4 a = *(const float4*)(ap + jj * 4);
        short4 sv = {bf16of(v.x * a.x), bf16of(v.y * a.y), bf16of(v.z * a.z),
                     bf16of(v.w * a.w)};
        *(short4*)(&Fs[m * PITCH + q * 16 + jj * 4]) = sv;
      }
    }
    {  // stage fw: o = t&127, q = t>>7
      const int o = t & 127, q = t >> 7;
      const float* wp = fw + (size_t)o * 256 + kk + q * 32;
#pragma unroll
      for (int jj = 0; jj < 8; ++jj) {
        const float4 v = *(const float4*)(wp + jj * 4);
        short4 sv = {bf16of(v.x), bf16of(v.y), bf16of(v.z), bf16of(v.w)};
        *(short4*)(&Ws[o * PITCH + q * 32 + jj * 4]) = sv;
      }
    }
    __syncthreads();
#pragma unroll
    for (int ks = 0; ks < 2; ++ks) {
      const int ko = ks * 32 + lk;
      s16x8 af[2];
#pragma unroll
      for (int i = 0; i < 2; ++i)
        af[i] = *(const s16x8*)(&Fs[(((w & 1) * 2 + i) * 16 + lrow) * PITCH + ko]);
#pragma unroll
      for (int j = 0; j < 4; ++j) {
        const s16x8 bfr = *(const s16x8*)(&Ws[(((w >> 1) * 4 + j) * 16 + lrow) * PITCH + ko]);
#pragma unroll
        for (int i = 0; i < 2; ++i)
          acc[i][j] = __builtin_amdgcn_mfma_f32_16x16x32_bf16(af[i], bfr, acc[i][j], 0, 0, 0);
      }
    }
  }
#pragma unroll
  for (int j = 0; j < 4; ++j) {
    const int o = ((w >> 1) * 4 + j) * 16 + lrow;  // C col = lane&15 -> o
    const float bias = fb[o];
#pragma unroll
    for (int i = 0; i < 2; ++i) {
      const int hw = hw0 + ((w & 1) * 2 + i) * 16 + (lane >> 4) * 4;
      f32x4 v = acc[i][j];
      v.x += bias;
      v.y += bias;
      v.z += bias;
      v.w += bias;
      *(f32x4*)(out + (size_t)img * 524288 + (size_t)o * 4096 + hw) = v;
    }
  }
}

extern "C" void kernel_launch(void* const* d_in, const int* in_sizes, int n_in,
                              void* d_out, int out_size, void* d_ws, size_t ws_size,
                              hipStream_t stream) {
  const float* x = (const float*)d_in[0];
  const float* w1 = (const float*)d_in[1];
  const float* w3 = (const float*)d_in[2];
  const float* b3 = (const float*)d_in[3];
  const float* lw = (const float*)d_in[4];
  const float* lb = (const float*)d_in[5];
  const float* ca1 = (const float*)d_in[6];
  const float* ca2 = (const float*)d_in[7];
  const float* fw = (const float*)d_in[8];
  const float* fb = (const float*)d_in[9];
  const float* binit = (const float*)d_in[10];

  float* ws = (float*)d_ws;
  float* bufA = ws;            // y -> xl -> feat   (M*256)
  float* bufB = ws + 4194304;  // xm                (M*256)
  float* psum = ws + 8388608;  // 4*64*256
  float* pmax = psum + 65536;
  float* attv = pmax + 65536;  // 1024
  float* out = (float*)d_out;
  float* out_att = out + 2097152;

  const dim3 blk(256);
  k_conv1x1<<<dim3(256), blk, 0, stream>>>(x, w1, bufA);
  k_dwconv<<<dim3(4096), blk, 0, stream>>>(bufA, w3, b3, bufB);
  k_lower<<<dim3(256), blk, 0, stream>>>(bufB, lw, lb, bufA);
  k_em_fast<<<dim3(4096), blk, 0, stream>>>(bufA, binit, bufB, bufA);
  k_em_slow<<<dim3(4096), blk, 0, stream>>>(bufA, binit, bufB, bufA);
  k_pool1<<<dim3(256), blk, 0, stream>>>(bufA, psum, pmax);
  k_att<<<dim3(4), blk, 0, stream>>>(psum, pmax, ca1, ca2, attv, out_att);
  k_fc<<<dim3(256), blk, 0, stream>>>(bufA, attv, fw, fb, out);
}